// Round 1
// baseline (513.951 us; speedup 1.0000x reference)
//
#include <hip/hip_runtime.h>

// LocallyConnectedLayer MI355X — R1: per-position bf16 MFMA GEMM (M=128,N=64,K=576->768 padded)
// Tj=2 spatial positions per block, c-chunk=8, XCD-swizzled tile order.
// out[b,o,i,j] = bias[o,i,j] + sum_{c,kh,kw} x[b,c,i+kh,j+kw] * W[c,o,i,j,kh,kw]
//   (weight dim0 = contraction channel c, dim1 = output channel o)

#define BDIM 256

typedef __bf16 bf16x4 __attribute__((ext_vector_type(4)));
typedef __bf16 bf16x8 __attribute__((ext_vector_type(8)));
typedef float f32x4 __attribute__((ext_vector_type(4)));

__device__ __forceinline__ unsigned short f2bf(float f) {
  union { float f; unsigned u; } v; v.f = f;
  unsigned r = v.u + 0x7fffu + ((v.u >> 16) & 1u);  // round-to-nearest-even
  return (unsigned short)(r >> 16);
}

// x:    [128,64,32,32]  strides b:65536 c:1024 h:32 w:1
// wgt:  [64(c),64(o),30,30,3,3] strides c:518400 o:8100 i:270 j:9 kh:3 kw:1
// bias: [64,30,30]
// out:  [128,64,30,30]  strides b:57600 o:900 ij:1

__global__ __launch_bounds__(256, 2) void lcl_kernel(
    const float* __restrict__ x, const float* __restrict__ wgt,
    const float* __restrict__ bias, float* __restrict__ out) {
  // --- tile mapping with XCD swizzle: each XCD gets a contiguous range of tiles
  int blk = blockIdx.x;                 // 0..449
  int xcd = blk & 7, sg = blk >> 3;
  int t = xcd * 56 + (xcd < 2 ? xcd : 2) + sg;   // exact partition of [0,450)
  int i  = t / 15;
  int j0 = (t % 15) * 2;                // block covers j0, j0+1

  // A slab: [b:128][g:24 (cc*3+kh)][dj:2][kw':4] bf16, +4 u16 pad per b-row (bank shift)
  // Bt:     [dj:2][o:64][k':96 + 8 pad] bf16 (k' = g*4 + kw', kw'==3 slot is zero)
  __shared__ __align__(16) unsigned short Aslab[128 * 196];   // 50176 B
  __shared__ __align__(16) unsigned short Bt[2 * 64 * 104];   // 26624 B

  const int tid  = threadIdx.x;
  const int wave = tid >> 6;
  const int lane = tid & 63;
  const int lrow = lane & 15;
  const int q    = lane >> 4;

  f32x4 acc[2][2][4];   // [mt][jj][nt]
#pragma unroll
  for (int a = 0; a < 2; ++a)
#pragma unroll
    for (int b = 0; b < 2; ++b)
#pragma unroll
      for (int c = 0; c < 4; ++c) acc[a][b][c] = f32x4{0.f, 0.f, 0.f, 0.f};

  for (int chunk = 0; chunk < 8; ++chunk) {
    const int c0 = chunk * 8;
    __syncthreads();   // protect LDS from previous chunk's readers

    // ---- stage A chunk: 128b x 8cc x 3kh x 5w' = 15360 x-elements, each -> up to 2 slab slots
    for (int idx = tid; idx < 15360; idx += BDIM) {
      int wp = idx % 5;
      int r  = idx / 5;
      int kh = r % 3; r /= 3;
      int cc = r & 7;
      int b  = r >> 3;
      int col = j0 + wp; col = col < 31 ? col : 31;   // clamp (only kw'=3 / zero-weight slot)
      float v = x[b * 65536 + (c0 + cc) * 1024 + (i + kh) * 32 + col];
      unsigned short bv = f2bf(v);
      int g    = cc * 3 + kh;
      int base = b * 196 + g * 8;          // [g][dj][kw'] = g*8 + dj*4 + kw'
      if (wp < 4)  Aslab[base + wp] = bv;            // dj=0, kw'=wp
      if (wp >= 1) Aslab[base + 4 + (wp - 1)] = bv;  // dj=1, kw'=wp-1
    }

    // ---- stage B chunk: 2j x 64o x 24g items, each 3 contiguous floats -> packed b64 (4th = 0)
    for (int idx = tid; idx < 3072; idx += BDIM) {
      int g  = idx % 24;
      int r  = idx / 24;
      int o  = r & 63;
      int jj = r >> 6;
      int cc = g / 3, kh = g - cc * 3;
      const float* gp = wgt + (c0 + cc) * 518400 + o * 8100 + (i * 30 + j0 + jj) * 9 + kh * 3;
      unsigned long long pk = (unsigned long long)f2bf(gp[0])
                            | ((unsigned long long)f2bf(gp[1]) << 16)
                            | ((unsigned long long)f2bf(gp[2]) << 32);
      *(unsigned long long*)&Bt[jj * 6656 + o * 104 + g * 4] = pk;
    }
    __syncthreads();

    // ---- 3 MFMA k-steps over this chunk's 96 padded k'
#pragma unroll
    for (int s = 0; s < 3; ++s) {
      bf16x8 bfr[2][4];
#pragma unroll
      for (int jj = 0; jj < 2; ++jj)
#pragma unroll
        for (int nt = 0; nt < 4; ++nt)
          bfr[jj][nt] = *reinterpret_cast<const bf16x8*>(
              &Bt[jj * 6656 + (nt * 16 + lrow) * 104 + s * 32 + q * 8]);
#pragma unroll
      for (int mt = 0; mt < 2; ++mt) {
        int b  = wave * 32 + mt * 16 + lrow;
        int ga = s * 8 + q * 2;
#pragma unroll
        for (int jj = 0; jj < 2; ++jj) {
          bf16x4 lo = *reinterpret_cast<const bf16x4*>(&Aslab[b * 196 + (ga * 2 + jj) * 4]);
          bf16x4 hi = *reinterpret_cast<const bf16x4*>(&Aslab[b * 196 + (ga * 2 + 2 + jj) * 4]);
          bf16x8 af = __builtin_shufflevector(lo, hi, 0, 1, 2, 3, 4, 5, 6, 7);
#pragma unroll
          for (int nt = 0; nt < 4; ++nt)
            acc[mt][jj][nt] = __builtin_amdgcn_mfma_f32_16x16x32_bf16(
                af, bfr[jj][nt], acc[mt][jj][nt], 0, 0, 0);
        }
      }
    }
  }

  // ---- epilogue: D[row=q*4+r][col=lrow]; row->b, col->o
#pragma unroll
  for (int jj = 0; jj < 2; ++jj) {
    int ij = i * 30 + j0 + jj;
#pragma unroll
    for (int nt = 0; nt < 4; ++nt) {
      int o = nt * 16 + lrow;
      float bv = bias[o * 900 + ij];
#pragma unroll
      for (int mt = 0; mt < 2; ++mt) {
#pragma unroll
        for (int r = 0; r < 4; ++r) {
          int b = wave * 32 + mt * 16 + q * 4 + r;
          out[b * 57600 + o * 900 + ij] = acc[mt][jj][nt][r] + bv;
        }
      }
    }
  }
}

extern "C" void kernel_launch(void* const* d_in, const int* in_sizes, int n_in,
                              void* d_out, int out_size, void* d_ws, size_t ws_size,
                              hipStream_t stream) {
  const float* x    = (const float*)d_in[0];
  const float* wgt  = (const float*)d_in[1];
  const float* bias = (const float*)d_in[2];
  float* out        = (float*)d_out;
  lcl_kernel<<<dim3(450), dim3(256), 0, stream>>>(x, wgt, bias, out);
}

// Round 2
// 318.126 us; speedup vs baseline: 1.6156x; 1.6156x over previous
//
#include <hip/hip_runtime.h>

// LocallyConnectedLayer MI355X — R2: MLP-restored staging.
// Per-position-pair bf16 MFMA GEMM (M=128, N=64, K=576, Tj=2, c-chunk 8).
// All staging loads batched into registers (2x dwordx2 per x-run, 9x dwordx2
// per weight-(c,o) pair), cross-chunk register prefetch, float2 epilogue.
// out[b,o,i,j] = bias[o,i,j] + sum_{c,kh,kw} x[b,c,i+kh,j+kw] * W[c,o,i,j,kh,kw]

#define BDIM 256

typedef __bf16 bf16x4 __attribute__((ext_vector_type(4)));
typedef __bf16 bf16x8 __attribute__((ext_vector_type(8)));
typedef float f32x4 __attribute__((ext_vector_type(4)));

__device__ __forceinline__ unsigned short f2bf(float f) {
  union { float f; unsigned u; } v; v.f = f;
  unsigned r = v.u + 0x7fffu + ((v.u >> 16) & 1u);  // RTNE
  return (unsigned short)(r >> 16);
}
__device__ __forceinline__ unsigned long long pk3(unsigned short a, unsigned short b,
                                                  unsigned short c) {
  return (unsigned long long)a | ((unsigned long long)b << 16) | ((unsigned long long)c << 32);
}

// x:    [128,64,32,32]  strides b:65536 c:1024 h:32 w:1
// wgt:  [64(c),64(o),30,30,3,3] strides c:518400 o:8100 (i*30+j):9 kh:3 kw:1
// bias: [64,30,30]; out: [128,64,30,30] strides b:57600 o:900 ij:1

__global__ __launch_bounds__(256, 2) void lcl_kernel(
    const float* __restrict__ x, const float* __restrict__ wgt,
    const float* __restrict__ bias, float* __restrict__ out) {
  // XCD swizzle: contiguous tile ranges per XCD (450 tiles over 8 XCDs)
  int blk = blockIdx.x;
  int xcd = blk & 7, sg = blk >> 3;
  int t = xcd * 56 + (xcd < 2 ? xcd : 2) + sg;   // exact partition of [0,450)
  int i  = t / 15;
  int j0 = (t % 15) * 2;                         // even
  int ij0 = i * 30 + j0;                         // even

  // A slab: [b:128][g:24][dj:2][kw':4] + 4 u16 row pad; Bt: [dj:2][o:64][96+8]
  __shared__ __align__(16) unsigned short Aslab[128 * 196];   // 50176 B
  __shared__ __align__(16) unsigned short Bt[2 * 64 * 104];   // 26624 B

  const int tid  = threadIdx.x;
  const int wave = tid >> 6;
  const int lane = tid & 63;
  const int lrow = lane & 15;
  const int q    = lane >> 4;

  f32x4 acc[2][2][4];
#pragma unroll
  for (int a = 0; a < 2; ++a)
#pragma unroll
    for (int b = 0; b < 2; ++b)
#pragma unroll
      for (int c = 0; c < 4; ++c) acc[a][b][c] = f32x4{0.f, 0.f, 0.f, 0.f};

  // prefetch registers: 12 x-runs (2 dwordx2 each) + 2 weight pairs (9 dwordx2)
  float2 av[12][2];
  float2 wv[2][9];

#define LOAD_CHUNK(C0)                                                          \
  {                                                                             \
    const int c0_ = (C0);                                                       \
    _Pragma("unroll")                                                           \
    for (int k = 0; k < 12; ++k) {                                              \
      int r  = tid + k * 256;                                                   \
      int kh = r % 3;                                                           \
      int cc = (r / 3) & 7;                                                     \
      int b  = r / 24;                                                          \
      const float2* xp = (const float2*)(x + b * 65536 + (c0_ + cc) * 1024 +    \
                                         (i + kh) * 32 + j0);                   \
      av[k][0] = xp[0];                                                         \
      av[k][1] = xp[1];                                                         \
    }                                                                           \
    _Pragma("unroll")                                                           \
    for (int p = 0; p < 2; ++p) {                                               \
      int pr = tid + p * 256;                                                   \
      int o = pr & 63, cc = pr >> 6;                                            \
      const float2* wp = (const float2*)(wgt + (c0_ + cc) * 518400 + o * 8100 + \
                                         ij0 * 9);                              \
      _Pragma("unroll")                                                         \
      for (int e = 0; e < 9; ++e) wv[p][e] = wp[e];                             \
    }                                                                           \
  }

  LOAD_CHUNK(0)

  for (int chunk = 0; chunk < 8; ++chunk) {
    if (chunk) __syncthreads();   // previous MFMA phase done reading LDS

    // ---- convert + LDS write from registers
#pragma unroll
    for (int k = 0; k < 12; ++k) {
      int r  = tid + k * 256;
      int kh = r % 3;
      int cc = (r / 3) & 7;
      int b  = r / 24;
      int g  = cc * 3 + kh;
      unsigned short h0 = f2bf(av[k][0].x), h1 = f2bf(av[k][0].y);
      unsigned short h2 = f2bf(av[k][1].x), h3 = f2bf(av[k][1].y);
      *(unsigned long long*)&Aslab[b * 196 + g * 8]     = pk3(h0, h1, h2);  // dj=0
      *(unsigned long long*)&Aslab[b * 196 + g * 8 + 4] = pk3(h1, h2, h3);  // dj=1
    }
#pragma unroll
    for (int p = 0; p < 2; ++p) {
      int pr = tid + p * 256;
      int o = pr & 63, cc = pr >> 6;
#pragma unroll
      for (int jj = 0; jj < 2; ++jj)
#pragma unroll
        for (int kh = 0; kh < 3; ++kh) {
          int e0 = jj * 9 + kh * 3;  // compile-time after unroll
          float f0 = (e0 & 1) ? wv[p][e0 >> 1].y : wv[p][e0 >> 1].x;
          float f1 = ((e0 + 1) & 1) ? wv[p][(e0 + 1) >> 1].y : wv[p][(e0 + 1) >> 1].x;
          float f2v = ((e0 + 2) & 1) ? wv[p][(e0 + 2) >> 1].y : wv[p][(e0 + 2) >> 1].x;
          *(unsigned long long*)&Bt[jj * 6656 + o * 104 + (cc * 3 + kh) * 4] =
              pk3(f2bf(f0), f2bf(f1), f2bf(f2v));
        }
    }
    __syncthreads();

    // ---- prefetch next chunk's globals (overlaps MFMA phase)
    if (chunk < 7) LOAD_CHUNK((chunk + 1) * 8)

    // ---- 3 MFMA k-steps (96 padded k' per chunk)
#pragma unroll
    for (int s = 0; s < 3; ++s) {
      bf16x8 bfr[2][4];
#pragma unroll
      for (int jj = 0; jj < 2; ++jj)
#pragma unroll
        for (int nt = 0; nt < 4; ++nt)
          bfr[jj][nt] = *reinterpret_cast<const bf16x8*>(
              &Bt[jj * 6656 + (nt * 16 + lrow) * 104 + s * 32 + q * 8]);
#pragma unroll
      for (int mt = 0; mt < 2; ++mt) {
        int b  = wave * 32 + mt * 16 + lrow;
        int ga = s * 8 + q * 2;
#pragma unroll
        for (int jj = 0; jj < 2; ++jj) {
          bf16x4 lo = *reinterpret_cast<const bf16x4*>(&Aslab[b * 196 + (ga * 2 + jj) * 4]);
          bf16x4 hi = *reinterpret_cast<const bf16x4*>(&Aslab[b * 196 + (ga * 2 + 2 + jj) * 4]);
          bf16x8 af = __builtin_shufflevector(lo, hi, 0, 1, 2, 3, 4, 5, 6, 7);
#pragma unroll
          for (int nt = 0; nt < 4; ++nt)
            acc[mt][jj][nt] = __builtin_amdgcn_mfma_f32_16x16x32_bf16(
                af, bfr[jj][nt], acc[mt][jj][nt], 0, 0, 0);
        }
      }
    }
  }

  // ---- epilogue: D[row=q*4+r][col=lrow]; row->b, col->o; float2 over (ij0, ij0+1)
#pragma unroll
  for (int nt = 0; nt < 4; ++nt) {
    int o = nt * 16 + lrow;
    float2 bv = *(const float2*)(bias + o * 900 + ij0);
#pragma unroll
    for (int mt = 0; mt < 2; ++mt) {
#pragma unroll
      for (int r = 0; r < 4; ++r) {
        int b = wave * 32 + mt * 16 + q * 4 + r;
        float2 res;
        res.x = acc[mt][0][nt][r] + bv.x;
        res.y = acc[mt][1][nt][r] + bv.y;
        *(float2*)(out + b * 57600 + o * 900 + ij0) = res;
      }
    }
  }
}

extern "C" void kernel_launch(void* const* d_in, const int* in_sizes, int n_in,
                              void* d_out, int out_size, void* d_ws, size_t ws_size,
                              hipStream_t stream) {
  const float* x    = (const float*)d_in[0];
  const float* wgt  = (const float*)d_in[1];
  const float* bias = (const float*)d_in[2];
  float* out        = (float*)d_out;
  lcl_kernel<<<dim3(450), dim3(256), 0, stream>>>(x, wgt, bias, out);
}